// Round 9
// baseline (128.669 us; speedup 1.0000x reference)
//
#include <hip/hip_runtime.h>

#define BB 8
#define HH 512
#define WW 512
#define HW (HH * WW)
#define STRIP 8    // rows marched per thread

__device__ __forceinline__ int reflect512(int v) {
    v = v < 0 ? -v : v;
    return v >= 512 ? 1022 - v : v;
}

// One thread per output column segment: window (7x7x3) lives in registers,
// rotated with a mod-7 slot scheme (all indices compile-time -> no scratch).
// Per step only the incoming row (7 cols x 3 ch) is loaded from global.
__global__ __launch_bounds__(256, 4) void bilateral_march(const float* __restrict__ in,
                                                          float* __restrict__ out) {
    const int blk   = blockIdx.x;
    const int b     = blk >> 7;          // 128 blocks per image
    const int rem   = blk & 127;
    const int strip = rem >> 1;          // 0..63
    const int xh    = rem & 1;
    const int x     = xh * 256 + threadIdx.x;
    const int ys    = strip * STRIP;

    const float* __restrict__ p0 = in + (size_t)b * 3 * HW;
    const float* __restrict__ p1 = p0 + HW;
    const float* __restrict__ p2 = p1 + HW;

    // reflected column indices (computed once; borders handled here)
    int colo[7];
    #pragma unroll
    for (int c = 0; c < 7; ++c) colo[c] = reflect512(x - 3 + c);

    // rolling window: slot (k+j)%7 holds image row ys+k-3+j at step k
    float w0[7][7], w1[7][7], w2[7][7];
    #pragma unroll
    for (int j = 0; j < 7; ++j) {
        int rb = reflect512(ys - 3 + j) * WW;
        #pragma unroll
        for (int c = 0; c < 7; ++c) {
            int o = rb + colo[c];
            w0[j][c] = p0[o]; w1[j][c] = p1[o]; w2[j][c] = p2[o];
        }
    }

    // log2 of unnormalized 1-D spatial gaussian (normalization cancels in num/den)
    const float ls7[7] = {-0.01472138f, -0.00654284f, -0.00163571f, 0.f,
                          -0.00163571f, -0.00654284f, -0.01472138f};
    const float K2 = -0.00721347520445f;   // (-0.5/10^2) * log2(e)

    #pragma unroll
    for (int k = 0; k < STRIP; ++k) {
        // prefetch next window row into temps (becomes slot k%7 at step k+1);
        // issued before the ~1100-cycle tap block so latency is hidden by ILP
        float t0[7], t1[7], t2[7];
        if (k < STRIP - 1) {
            int rb = reflect512(ys + k + 4) * WW;
            #pragma unroll
            for (int c = 0; c < 7; ++c) {
                int o = rb + colo[c];
                t0[c] = p0[o]; t1[c] = p1[o]; t2[c] = p2[o];
            }
        }

        const int cs = (k + 3) % 7;        // compile-time
        const float c0 = w0[cs][3], c1 = w1[cs][3], c2 = w2[cs][3];
        float n0 = 0.f, n1 = 0.f, n2 = 0.f, dn = 0.f;

        #pragma unroll
        for (int j = 0; j < 7; ++j) {
            const int s = (k + j) % 7;     // compile-time
            #pragma unroll
            for (int c = 0; c < 7; ++c) {
                float a0 = w0[s][c], a1 = w1[s][c], a2 = w2[s][c];
                float d  = fabsf(a0 - c0) + fabsf(a1 - c1) + fabsf(a2 - c2);
                float wt = __builtin_amdgcn_exp2f(fmaf(K2, d * d, ls7[j] + ls7[c]));
                n0 += wt * a0; n1 += wt * a1; n2 += wt * a2; dn += wt;
            }
        }

        const float inv = 1.0f / dn;
        size_t ob = (size_t)b * 3 * HW + (size_t)(ys + k) * WW + x;
        out[ob]          = n0 * inv;
        out[ob + HW]     = n1 * inv;
        out[ob + 2 * HW] = n2 * inv;

        if (k < STRIP - 1) {               // rotate: new row -> slot k%7 (dead top row)
            const int ns = k % 7;
            #pragma unroll
            for (int c = 0; c < 7; ++c) {
                w0[ns][c] = t0[c]; w1[ns][c] = t1[c]; w2[ns][c] = t2[c];
            }
        }
    }
}

extern "C" void kernel_launch(void* const* d_in, const int* in_sizes, int n_in,
                              void* d_out, int out_size, void* d_ws, size_t ws_size,
                              hipStream_t stream) {
    const float* in = (const float*)d_in[0];
    float* out = (float*)d_out;
    int blocks = BB * (WW / 256) * (HH / STRIP);   // 8 * 2 * 64 = 1024
    bilateral_march<<<blocks, 256, 0, stream>>>(in, out);
}

// Round 10
// 46.475 us; speedup vs baseline: 2.7686x; 2.7686x over previous
//
#include <hip/hip_runtime.h>

#define BB 8
#define HH 512
#define WW 512
#define HW (HH * WW)
#define STRIP 8    // rows marched per thread

__device__ __forceinline__ int reflect512(int v) {
    v = v < 0 ? -v : v;
    return v >= 512 ? 1022 - v : v;
}

// One thread per output column segment: window (7x7x3) lives in registers,
// rotated with a mod-7 slot scheme (all indices compile-time -> no scratch).
// Per step only the incoming row (7 cols x 3 ch) is loaded from global.
// NOTE: min-waves stays at 2 — (256,4) forces VGPR<=64 and spills the whole
// window to scratch (R9: WRITE_SIZE 262 MB, 128 us). Demand is ~108 VGPR;
// 4 waves/SIMD is already reachable at 108 without any cap.
__global__ __launch_bounds__(256, 2) void bilateral_march(const float* __restrict__ in,
                                                          float* __restrict__ out) {
    const int blk   = blockIdx.x;
    const int b     = blk >> 7;          // 128 blocks per image
    const int rem   = blk & 127;
    const int strip = rem >> 1;          // 0..63
    const int xh    = rem & 1;
    const int x     = xh * 256 + threadIdx.x;
    const int ys    = strip * STRIP;

    const float* __restrict__ p0 = in + (size_t)b * 3 * HW;
    const float* __restrict__ p1 = p0 + HW;
    const float* __restrict__ p2 = p1 + HW;

    // reflected column indices (computed once; borders handled here)
    int colo[7];
    #pragma unroll
    for (int c = 0; c < 7; ++c) colo[c] = reflect512(x - 3 + c);

    // rolling window: slot (k+j)%7 holds image row ys+k-3+j at step k
    float w0[7][7], w1[7][7], w2[7][7];
    #pragma unroll
    for (int j = 0; j < 7; ++j) {
        int rb = reflect512(ys - 3 + j) * WW;
        #pragma unroll
        for (int c = 0; c < 7; ++c) {
            int o = rb + colo[c];
            w0[j][c] = p0[o]; w1[j][c] = p1[o]; w2[j][c] = p2[o];
        }
    }

    // log2 of unnormalized 1-D spatial gaussian (normalization cancels in num/den)
    const float ls7[7] = {-0.01472138f, -0.00654284f, -0.00163571f, 0.f,
                          -0.00163571f, -0.00654284f, -0.01472138f};
    const float K2 = -0.00721347520445f;   // (-0.5/10^2) * log2(e)

    #pragma unroll
    for (int k = 0; k < STRIP; ++k) {
        // prefetch next window row into temps (becomes slot k%7 at step k+1);
        // issued before the ~1100-cycle tap block so latency is hidden by ILP
        float t0[7], t1[7], t2[7];
        if (k < STRIP - 1) {
            int rb = reflect512(ys + k + 4) * WW;
            #pragma unroll
            for (int c = 0; c < 7; ++c) {
                int o = rb + colo[c];
                t0[c] = p0[o]; t1[c] = p1[o]; t2[c] = p2[o];
            }
        }

        const int cs = (k + 3) % 7;        // compile-time
        const float c0 = w0[cs][3], c1 = w1[cs][3], c2 = w2[cs][3];
        float n0 = 0.f, n1 = 0.f, n2 = 0.f, dn = 0.f;

        #pragma unroll
        for (int j = 0; j < 7; ++j) {
            const int s = (k + j) % 7;     // compile-time
            #pragma unroll
            for (int c = 0; c < 7; ++c) {
                float a0 = w0[s][c], a1 = w1[s][c], a2 = w2[s][c];
                float d  = fabsf(a0 - c0) + fabsf(a1 - c1) + fabsf(a2 - c2);
                float wt = __builtin_amdgcn_exp2f(fmaf(K2, d * d, ls7[j] + ls7[c]));
                n0 += wt * a0; n1 += wt * a1; n2 += wt * a2; dn += wt;
            }
        }

        const float inv = 1.0f / dn;
        size_t ob = (size_t)b * 3 * HW + (size_t)(ys + k) * WW + x;
        out[ob]          = n0 * inv;
        out[ob + HW]     = n1 * inv;
        out[ob + 2 * HW] = n2 * inv;

        if (k < STRIP - 1) {               // rotate: new row -> slot k%7 (dead top row)
            const int ns = k % 7;
            #pragma unroll
            for (int c = 0; c < 7; ++c) {
                w0[ns][c] = t0[c]; w1[ns][c] = t1[c]; w2[ns][c] = t2[c];
            }
        }
    }
}

extern "C" void kernel_launch(void* const* d_in, const int* in_sizes, int n_in,
                              void* d_out, int out_size, void* d_ws, size_t ws_size,
                              hipStream_t stream) {
    const float* in = (const float*)d_in[0];
    float* out = (float*)d_out;
    int blocks = BB * (WW / 256) * (HH / STRIP);   // 8 * 2 * 64 = 1024
    bilateral_march<<<blocks, 256, 0, stream>>>(in, out);
}